// Round 4
// baseline (191.443 us; speedup 1.0000x reference)
//
#include <hip/hip_runtime.h>

// ---------------- problem constants ----------------
#define T_LEN   1048576
#define NPAD    1049600            // T_LEN + 2*512
#define NFRAMES 2049
#define BATCH   8
#define NJ      (BATCH * NFRAMES)  // 16392 total frames
#define NSEG    2050               // seg rows per batch
#define SMAX    (BATCH * NSEG - 1) // 16399
#define CUT     513
#define MROWS   1026
#define MPAD    1152               // 9 tiles of 128
#define OUT_BF  (CUT * NFRAMES)
#define NJT     129                // j-tiles of 128
#define PAD_BLOCKS (BATCH * (NPAD / 8) / 256)   // 4100

typedef __attribute__((ext_vector_type(8))) short bf16x8_t;
typedef __attribute__((ext_vector_type(4))) float f32x4_t;

static __device__ __forceinline__ ushort f2bf(float f) {
    union { float f; unsigned u; } a;
    a.f = f;
    unsigned r = a.u + 0x7fffu + ((a.u >> 16) & 1u);
    return (ushort)(r >> 16);
}

static __device__ __forceinline__ void gl_lds16(const ushort* g, ushort* s) {
    __builtin_amdgcn_global_load_lds(
        (__attribute__((address_space(1))) void*)g,
        (__attribute__((address_space(3))) void*)s,
        16, 0, 0);
}

// ---------------- merged prep: reflect-pad + basis rearrange ----------------
__global__ void prep_kernel(const float* __restrict__ in, const float* __restrict__ fb,
                            ushort* __restrict__ xpad, ushort* __restrict__ A2) {
    const int tid = threadIdx.x;
    if (blockIdx.x < PAD_BLOCKS) {
        int g  = blockIdx.x * 256 + tid;
        int b  = g / (NPAD / 8);
        int c  = g - b * (NPAD / 8);
        int i0 = c * 8;
        const float* inb = in + (size_t)b * T_LEN;
        ushort o[8];
        if (i0 >= 512 && i0 + 7 < 512 + T_LEN) {
            const float4 v0 = *(const float4*)(inb + (i0 - 512));
            const float4 v1 = *(const float4*)(inb + (i0 - 512) + 4);
            o[0]=f2bf(v0.x); o[1]=f2bf(v0.y); o[2]=f2bf(v0.z); o[3]=f2bf(v0.w);
            o[4]=f2bf(v1.x); o[5]=f2bf(v1.y); o[6]=f2bf(v1.z); o[7]=f2bf(v1.w);
        } else {
            for (int t = 0; t < 8; ++t) {
                int i = i0 + t;
                int src = (i < 512) ? (512 - i)
                        : (i < 512 + T_LEN) ? (i - 512)
                        : (2 * T_LEN + 510 - i);
                o[t] = f2bf(inb[src]);
            }
        }
        *(ulonglong2*)(xpad + (size_t)b * NPAD + i0) = *(ulonglong2*)o;
    } else {
        int g  = (blockIdx.x - PAD_BLOCKS) * 256 + tid;
        int r  = g >> 8;
        int cq = (g & 255) * 4;
        ushort4 o;
        if (r < MROWS) {
            int f = r >> 1, h = r & 1;
            const float4 v = *(const float4*)(fb + (size_t)(f + h * CUT) * 1024 + cq);
            o = make_ushort4(f2bf(v.x), f2bf(v.y), f2bf(v.z), f2bf(v.w));
        } else {
            o = make_ushort4(0, 0, 0, 0);
        }
        *(ushort4*)(A2 + (size_t)r * 1024 + cq) = o;
    }
}

// ---------------- GEMM: A direct global->reg, B dbuf LDS, 1 barrier/kt ----------------
__global__ __launch_bounds__(256, 3) void gemm_kernel(
        const ushort* __restrict__ A2, const ushort* __restrict__ xpad,
        float* __restrict__ out, const float* __restrict__ epsp) {
    __shared__ __align__(16) ushort ldsB[2][136 * 64];   // 2 x 17 KB

    // XCD swizzle: all 9 m-blocks of a j-tile share bid%8 (same XCD)
    const int bid = blockIdx.x;
    const int jt  = (bid / 72) * 8 + (bid & 7);
    const int mt  = (bid >> 3) % 9;
    if (jt >= NJT) return;

    const int tid  = threadIdx.x;
    const int wave = tid >> 6, lane = tid & 63;
    const int quad = lane >> 4, l15 = lane & 15;
    const int m0 = mt * 128, j0 = jt * 128;
    const int wm = (wave >> 1) * 64, wj = (wave & 1) * 64;
    const int b0 = j0 / NFRAMES;
    const int S0 = j0 + b0;

    // ---- B staging addresses (16 issues cover rows 0..127, +1 extra 128..135) ----
    const int sr  = lane >> 3;
    const int sc8 = ((lane & 7) ^ sr) * 8;     // XOR-swizzled source chunk
    int boff[4], boffx;
    for (int t = 0; t < 4; ++t) {
        int S = S0 + (wave * 4 + t) * 8 + sr; if (S > SMAX) S = SMAX;
        int bb = S / NSEG, ss = S - bb * NSEG;
        boff[t] = bb * NPAD + ss * 512 + sc8;
    }
    {
        int S = S0 + 128 + sr; if (S > SMAX) S = SMAX;
        int bb = S / NSEG, ss = S - bb * NSEG;
        boffx = bb * NPAD + ss * 512 + sc8;
    }

    // ---- B fragment rows (handles batch-boundary shift) ----
    int r0base[4], r1base[4], r0s[4], r1s[4];
    for (int jx = 0; jx < 4; ++jx) {
        const int j  = j0 + wj + jx * 16 + l15;
        const int r0 = wj + jx * 16 + l15 + (j / NFRAMES - b0);
        const int r1 = r0 + 1;
        r0base[jx] = r0 * 64;  r0s[jx] = r0 & 7;
        r1base[jx] = r1 * 64;  r1s[jx] = r1 & 7;
    }

    // ---- A row pointers (direct global fragment loads; fully coalesced:
    //      per wave = 16 rows x one full 64B line) ----
    const ushort* arow[4];
    for (int i = 0; i < 4; ++i)
        arow[i] = A2 + (size_t)(m0 + wm + i * 16 + l15) * 1024 + quad * 8;

    f32x4_t acc[4][4] = {};

    // prologue: stage B tile 0
    {
        ushort* buf = &ldsB[0][0];
        #pragma unroll
        for (int t = 0; t < 4; ++t)
            gl_lds16(xpad + boff[t], buf + (wave * 4 + t) * 512);
        if (wave == 0) gl_lds16(xpad + boffx, buf + 16 * 512);
    }

    for (int kt = 0; kt < 8; ++kt) {
        __syncthreads();   // drains staging for buf[kt&1] (issued a full compute ago)
        if (kt < 7) {
            ushort* buf = &ldsB[(kt + 1) & 1][0];
            const int ko = (kt + 1) * 64;
            #pragma unroll
            for (int t = 0; t < 4; ++t)
                gl_lds16(xpad + boff[t] + ko, buf + (wave * 4 + t) * 512);
            if (wave == 0) gl_lds16(xpad + boffx + ko, buf + 16 * 512);
        }
        const ushort* bb_ = &ldsB[kt & 1][0];

        #pragma unroll
        for (int kk = 0; kk < 2; ++kk) {
            const int cb = kk * 4 + quad;
            const int ko = kt * 64 + kk * 32;
            bf16x8_t a0[4], a1[4], bf0[4], bf1[4];
            #pragma unroll
            for (int i = 0; i < 4; ++i) {
                a0[i] = *(const bf16x8_t*)(arow[i] + ko);
                a1[i] = *(const bf16x8_t*)(arow[i] + 512 + ko);
            }
            #pragma unroll
            for (int jx = 0; jx < 4; ++jx) {
                bf0[jx] = *(const bf16x8_t*)&bb_[r0base[jx] + ((cb ^ r0s[jx]) * 8)];
                bf1[jx] = *(const bf16x8_t*)&bb_[r1base[jx] + ((cb ^ r1s[jx]) * 8)];
            }
            #pragma unroll
            for (int i = 0; i < 4; ++i)
                #pragma unroll
                for (int jx = 0; jx < 4; ++jx) {
                    acc[i][jx] = __builtin_amdgcn_mfma_f32_16x16x32_bf16(
                        a0[i], bf0[jx], acc[i][jx], 0, 0, 0);
                    acc[i][jx] = __builtin_amdgcn_mfma_f32_16x16x32_bf16(
                        a1[i], bf1[jx], acc[i][jx], 0, 0, 0);
                }
        }
    }

    // ---- epilogue: C/D col=lane&15 (j), row=quad*4+reg (M) ----
    const float eps = *epsp;
    for (int tj = 0; tj < 4; ++tj) {
        const int j = j0 + wj + tj * 16 + l15;
        if (j >= NJ) continue;
        const int b = j / NFRAMES;
        const int n = j - b * NFRAMES;
        float* ob = out + (size_t)b * OUT_BF + n;
        for (int ti = 0; ti < 4; ++ti) {
            const int M  = m0 + wm + ti * 16 + quad * 4;
            const int f0 = M >> 1;
            f32x4_t a = acc[ti][tj];
            if (f0 < CUT)
                ob[(size_t)f0 * NFRAMES] = sqrtf(a.x * a.x + a.y * a.y + eps);
            if (f0 + 1 < CUT)
                ob[(size_t)(f0 + 1) * NFRAMES] = sqrtf(a.z * a.z + a.w * a.w + eps);
        }
    }
}

extern "C" void kernel_launch(void* const* d_in, const int* in_sizes, int n_in,
                              void* d_out, int out_size, void* d_ws, size_t ws_size,
                              hipStream_t stream) {
    const float* in   = (const float*)d_in[0];
    const float* fb   = (const float*)d_in[1];
    const float* epsp = (const float*)d_in[2];
    float* out = (float*)d_out;

    ushort* A2   = (ushort*)d_ws;
    ushort* xpad = (ushort*)((char*)d_ws + (size_t)MPAD * 1024 * 2);

    prep_kernel<<<dim3(PAD_BLOCKS + MPAD), dim3(256), 0, stream>>>(in, fb, xpad, A2);
    gemm_kernel<<<dim3(17 * 72), dim3(256), 0, stream>>>(A2, xpad, out, epsp);
}

// Round 5
// 124.987 us; speedup vs baseline: 1.5317x; 1.5317x over previous
//
#include <hip/hip_runtime.h>

// ---------------- problem constants ----------------
#define T_LEN   1048576
#define NPAD    1049600            // T_LEN + 2*512
#define NFRAMES 2049
#define BATCH   8
#define NJ      (BATCH * NFRAMES)  // 16392 total frames
#define NSEG    2050               // seg rows per batch
#define SMAX    (BATCH * NSEG - 1) // 16399
#define CUT     513
#define MROWS   1026
#define MPAD    1152               // 9 tiles of 128
#define OUT_BF  (CUT * NFRAMES)
#define NJT     129                // j-tiles of 128
#define PAD_BLOCKS (BATCH * (NPAD / 8) / 256)   // 4100

typedef __attribute__((ext_vector_type(8))) short bf16x8_t;
typedef __attribute__((ext_vector_type(4))) float f32x4_t;

static __device__ __forceinline__ ushort f2bf(float f) {
    union { float f; unsigned u; } a;
    a.f = f;
    unsigned r = a.u + 0x7fffu + ((a.u >> 16) & 1u);
    return (ushort)(r >> 16);
}

static __device__ __forceinline__ void gl_lds16(const ushort* g, ushort* s) {
    __builtin_amdgcn_global_load_lds(
        (__attribute__((address_space(1))) void*)g,
        (__attribute__((address_space(3))) void*)s,
        16, 0, 0);
}

// ---------------- merged prep: reflect-pad + basis rearrange ----------------
__global__ void prep_kernel(const float* __restrict__ in, const float* __restrict__ fb,
                            ushort* __restrict__ xpad, ushort* __restrict__ A2) {
    const int tid = threadIdx.x;
    if (blockIdx.x < PAD_BLOCKS) {
        int g  = blockIdx.x * 256 + tid;
        int b  = g / (NPAD / 8);
        int c  = g - b * (NPAD / 8);
        int i0 = c * 8;
        const float* inb = in + (size_t)b * T_LEN;
        ushort o[8];
        if (i0 >= 512 && i0 + 7 < 512 + T_LEN) {
            const float4 v0 = *(const float4*)(inb + (i0 - 512));
            const float4 v1 = *(const float4*)(inb + (i0 - 512) + 4);
            o[0]=f2bf(v0.x); o[1]=f2bf(v0.y); o[2]=f2bf(v0.z); o[3]=f2bf(v0.w);
            o[4]=f2bf(v1.x); o[5]=f2bf(v1.y); o[6]=f2bf(v1.z); o[7]=f2bf(v1.w);
        } else {
            for (int t = 0; t < 8; ++t) {
                int i = i0 + t;
                int src = (i < 512) ? (512 - i)
                        : (i < 512 + T_LEN) ? (i - 512)
                        : (2 * T_LEN + 510 - i);
                o[t] = f2bf(inb[src]);
            }
        }
        *(ulonglong2*)(xpad + (size_t)b * NPAD + i0) = *(ulonglong2*)o;
    } else {
        int g  = (blockIdx.x - PAD_BLOCKS) * 256 + tid;
        int r  = g >> 8;
        int cq = (g & 255) * 4;
        ushort4 o;
        if (r < MROWS) {
            int f = r >> 1, h = r & 1;
            const float4 v = *(const float4*)(fb + (size_t)(f + h * CUT) * 1024 + cq);
            o = make_ushort4(f2bf(v.x), f2bf(v.y), f2bf(v.z), f2bf(v.w));
        } else {
            o = make_ushort4(0, 0, 0, 0);
        }
        *(ushort4*)(A2 + (size_t)r * 1024 + cq) = o;
    }
}

// ---------------- GEMM (hop-split, BK=64, XOR-swizzled LDS, XCD-swizzled grid) ----
// C[m][j] = sum_{k'} A0[m][k']*seg(Sj)[k'] + A1[m][k']*seg(Sj+1)[k']
// LDS chunk c (16B) of row r holds global chunk c^(r&7) via per-lane source permute.
__global__ __launch_bounds__(256) void gemm_kernel(
        const ushort* __restrict__ A2, const ushort* __restrict__ xpad,
        float* __restrict__ out, const float* __restrict__ epsp) {
    __shared__ __align__(16) ushort ldsA0[128 * 64];
    __shared__ __align__(16) ushort ldsA1[128 * 64];
    __shared__ __align__(16) ushort ldsB [136 * 64];

    // XCD swizzle: all 9 m-blocks of one j-tile share bid%8 -> same XCD L2
    const int bid = blockIdx.x;
    const int jt  = (bid / 72) * 8 + (bid & 7);
    const int mt  = (bid >> 3) % 9;
    if (jt >= NJT) return;                 // uniform early-exit (before any barrier)

    const int tid  = threadIdx.x;
    const int wave = tid >> 6, lane = tid & 63;
    const int quad = lane >> 4, l15 = lane & 15;
    const int m0 = mt * 128;
    const int j0 = jt * 128;
    const int wm = (wave >> 1) * 64;
    const int wj = (wave & 1) * 64;

    const int b0 = j0 / NFRAMES;
    const int S0 = j0 + b0;                // global seg index of LDS B row 0

    const int sr  = lane >> 3;             // staged row within 8-row group
    const int sc8 = ((lane & 7) ^ sr) * 8; // XOR-swizzled source chunk (elems)

    int aoff[4], boff[4], boffx = 0;
    for (int t = 0; t < 4; ++t) {
        const int r = (wave * 4 + t) * 8 + sr;
        aoff[t] = (m0 + r) * 1024 + sc8;
        int S = S0 + r; if (S > SMAX) S = SMAX;
        int bb = S / NSEG, ss = S - bb * NSEG;
        boff[t] = bb * NPAD + ss * 512 + sc8;
    }
    {
        int S = S0 + 128 + sr; if (S > SMAX) S = SMAX;
        int bb = S / NSEG, ss = S - bb * NSEG;
        boffx = bb * NPAD + ss * 512 + sc8;
    }

    // per-lane B fragment base rows (handles batch-boundary shift)
    int rowb[4];
    for (int jx = 0; jx < 4; ++jx) {
        const int j = j0 + wj + jx * 16 + l15;
        rowb[jx] = wj + jx * 16 + l15 + (j / NFRAMES - b0);
    }

    f32x4_t acc[4][4] = {};

    for (int kt = 0; kt < 8; ++kt) {
        const int k0 = kt * 64;
        __syncthreads();
        for (int t = 0; t < 4; ++t) {
            gl_lds16(A2 + aoff[t] + k0,        &ldsA0[(wave * 4 + t) * 512]);
            gl_lds16(A2 + aoff[t] + 512 + k0,  &ldsA1[(wave * 4 + t) * 512]);
            gl_lds16(xpad + boff[t] + k0,      &ldsB [(wave * 4 + t) * 512]);
        }
        if (wave == 0) gl_lds16(xpad + boffx + k0, &ldsB[16 * 512]);
        __syncthreads();
        for (int kk = 0; kk < 2; ++kk) {
            const int cb = kk * 4 + quad;      // within-window chunk 0..7
            bf16x8_t a0[4], a1[4], bf0[4], bf1[4];
            const int asw = (cb ^ (l15 & 7)) * 8;
            for (int i = 0; i < 4; ++i) {
                const int ro = (wm + i * 16 + l15) * 64;
                a0[i] = *(const bf16x8_t*)&ldsA0[ro + asw];
                a1[i] = *(const bf16x8_t*)&ldsA1[ro + asw];
            }
            for (int jx = 0; jx < 4; ++jx) {
                const int r0 = rowb[jx];
                const int r1 = r0 + 1;
                bf0[jx] = *(const bf16x8_t*)&ldsB[r0 * 64 + ((cb ^ (r0 & 7)) * 8)];
                bf1[jx] = *(const bf16x8_t*)&ldsB[r1 * 64 + ((cb ^ (r1 & 7)) * 8)];
            }
            for (int i = 0; i < 4; ++i)
                for (int jx = 0; jx < 4; ++jx) {
                    acc[i][jx] = __builtin_amdgcn_mfma_f32_16x16x32_bf16(
                        a0[i], bf0[jx], acc[i][jx], 0, 0, 0);
                    acc[i][jx] = __builtin_amdgcn_mfma_f32_16x16x32_bf16(
                        a1[i], bf1[jx], acc[i][jx], 0, 0, 0);
                }
        }
    }

    // epilogue: C/D layout col=lane&15 (-> j), row=quad*4+reg (-> M)
    const float eps = *epsp;
    for (int tj = 0; tj < 4; ++tj) {
        const int j = j0 + wj + tj * 16 + l15;
        if (j >= NJ) continue;
        const int b = j / NFRAMES;
        const int n = j - b * NFRAMES;
        float* ob = out + (size_t)b * OUT_BF + n;
        for (int ti = 0; ti < 4; ++ti) {
            const int M  = m0 + wm + ti * 16 + quad * 4;
            const int f0 = M >> 1;
            f32x4_t a = acc[ti][tj];
            if (f0 < CUT)
                ob[(size_t)f0 * NFRAMES] = sqrtf(a.x * a.x + a.y * a.y + eps);
            if (f0 + 1 < CUT)
                ob[(size_t)(f0 + 1) * NFRAMES] = sqrtf(a.z * a.z + a.w * a.w + eps);
        }
    }
}

extern "C" void kernel_launch(void* const* d_in, const int* in_sizes, int n_in,
                              void* d_out, int out_size, void* d_ws, size_t ws_size,
                              hipStream_t stream) {
    const float* in   = (const float*)d_in[0];
    const float* fb   = (const float*)d_in[1];
    const float* epsp = (const float*)d_in[2];
    float* out = (float*)d_out;

    ushort* A2   = (ushort*)d_ws;
    ushort* xpad = (ushort*)((char*)d_ws + (size_t)MPAD * 1024 * 2);

    prep_kernel<<<dim3(PAD_BLOCKS + MPAD), dim3(256), 0, stream>>>(in, fb, xpad, A2);
    // grid: 17 groups x (8 j-tiles x 9 m-tiles); blocks with jt>=129 early-exit
    gemm_kernel<<<dim3(17 * 72), dim3(256), 0, stream>>>(A2, xpad, out, epsp);
}